// Round 1
// baseline (205.401 us; speedup 1.0000x reference)
//
#include <hip/hip_runtime.h>
#include <stdint.h>

#define BATCH 8
#define CIN   64
#define DH    32
#define NTOK  4096
#define LOG2E 1.4426950408889634f

typedef float f4  __attribute__((ext_vector_type(4)));
typedef short s8v __attribute__((ext_vector_type(8)));

static __device__ __forceinline__ short f2bf(float f) {
    union { float f; uint32_t u; } c; c.f = f;
    uint32_t u = c.u;
    uint32_t r = (u + 0x7fffu + ((u >> 16) & 1u)) >> 16;   // RNE truncate to bf16
    return (short)(r & 0xffffu);
}
static __device__ __forceinline__ uint32_t pk2(float a, float b) {
    return (uint32_t)(uint16_t)f2bf(a) | ((uint32_t)(uint16_t)f2bf(b) << 16);
}

// ---------------------------------------------------------------------------
// Kernel 1: QKV projections (+ wz bf16 conversion).
//   qbf[b][n][32]  = bf16( (Wq x + bq) * log2(e) )   (n-major, d contiguous)
//   kbf[b][n][32]  = bf16(  Wk x + bk )              (n-major, d contiguous)
//   vp : permuted V layout so attention A-fragments are contiguous:
//        key n -> cidx=n>>5, p=n&31, t=p>>4, qq=(p>>2)&3, r=p&3, j=t*4+r
//        vp[((b*128+cidx)*4+qq)*64 + ch][j]  (each [ch] row is 8 bf16 = 16 B)
// ---------------------------------------------------------------------------
__global__ __launch_bounds__(256) void proj_kernel(
    const float* __restrict__ h,
    const float* __restrict__ wq, const float* __restrict__ bq,
    const float* __restrict__ wk, const float* __restrict__ bk,
    const float* __restrict__ wv, const float* __restrict__ bv,
    const float* __restrict__ wz,
    short* __restrict__ qbf, short* __restrict__ kbf,
    short* __restrict__ vp,  short* __restrict__ wzb)
{
    __shared__ float wqt[64 * 36];   // transposed [c][o], padded stride 36 (16B aligned)
    __shared__ float wkt[64 * 36];
    __shared__ float wvt[64 * 68];   // [c][o] o=64, stride 68

    const int tid = threadIdx.x;
    for (int i = tid; i < 2048; i += 256) {
        int o = i >> 6, c = i & 63;
        wqt[c * 36 + o] = wq[i];
        wkt[c * 36 + o] = wk[i];
    }
    for (int i = tid; i < 4096; i += 256) {
        int o = i >> 6, c = i & 63;
        wvt[c * 68 + o] = wv[i];
    }
    if (blockIdx.x == 0) {
        for (int i = tid; i < 4096; i += 256) wzb[i] = f2bf(wz[i]);
    }
    __syncthreads();

    const int b  = blockIdx.x & 7;
    const int nc = blockIdx.x >> 3;
    const int n  = nc * 256 + tid;
    const float* xcol = h + (size_t)b * CIN * NTOK + n;

    // preload this token's channel vector (coalesced across lanes)
    float xr[64];
    #pragma unroll
    for (int c = 0; c < 64; ++c) xr[c] = xcol[c * NTOK];

    // ---- q, k ----
    float qa[32], ka[32];
    #pragma unroll
    for (int o = 0; o < 32; ++o) { qa[o] = bq[o]; ka[o] = bk[o]; }
    #pragma unroll
    for (int c = 0; c < 64; ++c) {
        float xv = xr[c];
        #pragma unroll
        for (int o4 = 0; o4 < 8; ++o4) {
            f4 w4 = *(const f4*)&wqt[c * 36 + o4 * 4];
            f4 k4 = *(const f4*)&wkt[c * 36 + o4 * 4];
            #pragma unroll
            for (int i = 0; i < 4; ++i) {
                qa[o4 * 4 + i] += w4[i] * xv;
                ka[o4 * 4 + i] += k4[i] * xv;
            }
        }
    }
    {
        uint32_t* qrow = (uint32_t*)(qbf + (size_t)(b * NTOK + n) * DH);
        uint32_t* krow = (uint32_t*)(kbf + (size_t)(b * NTOK + n) * DH);
        #pragma unroll
        for (int g = 0; g < 16; ++g) {
            qrow[g] = pk2(qa[2 * g] * LOG2E, qa[2 * g + 1] * LOG2E);
            krow[g] = pk2(ka[2 * g], ka[2 * g + 1]);
        }
    }

    // ---- v ----
    float va[64];
    #pragma unroll
    for (int o = 0; o < 64; ++o) va[o] = bv[o];
    #pragma unroll
    for (int c = 0; c < 64; ++c) {
        float xv = xr[c];
        #pragma unroll
        for (int o4 = 0; o4 < 16; ++o4) {
            f4 w4 = *(const f4*)&wvt[c * 68 + o4 * 4];
            #pragma unroll
            for (int i = 0; i < 4; ++i) va[o4 * 4 + i] += w4[i] * xv;
        }
    }
    {
        const int cidx = n >> 5, p = n & 31;
        const int t = p >> 4, qq = (p >> 2) & 3, r = p & 3;
        const int j = t * 4 + r;
        short* vdst = vp + ((size_t)((b * 128 + cidx) * 4 + qq) * 64) * 8 + j;
        #pragma unroll
        for (int ch = 0; ch < 64; ++ch) vdst[ch * 8] = f2bf(va[ch]);
    }
}

// ---------------------------------------------------------------------------
// Kernel 2: fused flash attention (transposed-S) + out-projection + residual.
// One wave = 16 queries. Block = 4 waves = 64 queries. grid = (b=8, qblock=64).
// ---------------------------------------------------------------------------
__global__ __launch_bounds__(256) void attn_kernel(
    const float* __restrict__ h,  const float* __restrict__ bz,
    const short* __restrict__ qbf, const short* __restrict__ kbf,
    const short* __restrict__ vp,  const short* __restrict__ wzb,
    float* __restrict__ out)
{
    __shared__ short zl[4][16 * 72];   // per-wave z transpose buffer [n][c], stride 72

    const int b    = blockIdx.x;           // XCD-affine: linear%8 == b
    const int qb   = blockIdx.y;
    const int tid  = threadIdx.x;
    const int wave = tid >> 6;
    const int lane = tid & 63;
    const int ln   = lane & 15;
    const int quad = lane >> 4;
    const int n0   = qb * 64 + wave * 16;

    // Q as B-operand: B[d=quad*8+j][n=ln]  (constant over the K loop)
    const s8v qf = *(const s8v*)(qbf + (size_t)(b * NTOK + n0 + ln) * DH + quad * 8);

    f4 acc[4];
    #pragma unroll
    for (int ct = 0; ct < 4; ++ct) acc[ct] = (f4){0.f, 0.f, 0.f, 0.f};
    float m_i = -1e30f, l_i = 0.f;

    const short* kb = kbf + (size_t)b * NTOK * DH;
    const s8v*   vb = (const s8v*)(vp + (size_t)b * NTOK * CIN);
    const f4 zf4 = {0.f, 0.f, 0.f, 0.f};

    for (int kt = 0; kt < NTOK; kt += 32) {
        // K tiles as A-operand: A[key=ln (+16t)][d=quad*8+j]
        s8v k0 = *(const s8v*)(kb + (kt + ln) * DH + quad * 8);
        s8v k1 = *(const s8v*)(kb + (kt + 16 + ln) * DH + quad * 8);
        // V A-fragments (permuted layout): A[c=ct*16+ln][slot=quad*8+j]
        const s8v* vg = vb + (size_t)((kt >> 5) * 4 + quad) * 64 + ln;
        s8v v0 = vg[0], v1 = vg[16], v2 = vg[32], v3 = vg[48];

        // S^T tiles: D[key][query], scores already in log2 domain
        f4 s0 = __builtin_amdgcn_mfma_f32_16x16x32_bf16(k0, qf, zf4, 0, 0, 0);
        f4 s1 = __builtin_amdgcn_mfma_f32_16x16x32_bf16(k1, qf, zf4, 0, 0, 0);

        // online softmax, per-query stats in-lane (query = ln, dup across quads)
        float tm = fmaxf(fmaxf(fmaxf(s0[0], s0[1]), fmaxf(s0[2], s0[3])),
                         fmaxf(fmaxf(s1[0], s1[1]), fmaxf(s1[2], s1[3])));
        tm = fmaxf(tm, __shfl_xor(tm, 16));
        tm = fmaxf(tm, __shfl_xor(tm, 32));
        float mn = fmaxf(m_i, tm);
        float al = __builtin_amdgcn_exp2f(m_i - mn);
        f4 p0, p1;
        #pragma unroll
        for (int r = 0; r < 4; ++r) {
            p0[r] = __builtin_amdgcn_exp2f(s0[r] - mn);
            p1[r] = __builtin_amdgcn_exp2f(s1[r] - mn);
        }
        float rs = (p0[0] + p0[1]) + (p0[2] + p0[3]) +
                   (p1[0] + p1[1]) + (p1[2] + p1[3]);
        rs += __shfl_xor(rs, 16);
        rs += __shfl_xor(rs, 32);
        l_i = l_i * al + rs;
        m_i = mn;
        #pragma unroll
        for (int ct = 0; ct < 4; ++ct) acc[ct] *= al;

        // P as B-operand in-register: slot quad*8 + t*4 + r <-> key 16t+4*quad+r
        s8v pf;
        pf[0] = f2bf(p0[0]); pf[1] = f2bf(p0[1]); pf[2] = f2bf(p0[2]); pf[3] = f2bf(p0[3]);
        pf[4] = f2bf(p1[0]); pf[5] = f2bf(p1[1]); pf[6] = f2bf(p1[2]); pf[7] = f2bf(p1[3]);

        acc[0] = __builtin_amdgcn_mfma_f32_16x16x32_bf16(v0, pf, acc[0], 0, 0, 0);
        acc[1] = __builtin_amdgcn_mfma_f32_16x16x32_bf16(v1, pf, acc[1], 0, 0, 0);
        acc[2] = __builtin_amdgcn_mfma_f32_16x16x32_bf16(v2, pf, acc[2], 0, 0, 0);
        acc[3] = __builtin_amdgcn_mfma_f32_16x16x32_bf16(v3, pf, acc[3], 0, 0, 0);
    }

    // normalize (per-query l in-lane) and transpose z through per-wave LDS
    const float rl = __builtin_amdgcn_rcpf(l_i);
    #pragma unroll
    for (int ct = 0; ct < 4; ++ct)
        #pragma unroll
        for (int r = 0; r < 4; ++r)
            zl[wave][ln * 72 + ct * 16 + quad * 4 + r] = f2bf(acc[ct][r] * rl);
    // same-wave DS write->read: compiler inserts lgkmcnt wait; no barrier needed

    // z as B-operand: B[c=h2*32+quad*8+j][n=ln]
    s8v zf0 = *(const s8v*)&zl[wave][ln * 72 + quad * 8];
    s8v zf1 = *(const s8v*)&zl[wave][ln * 72 + 32 + quad * 8];

    #pragma unroll
    for (int ot = 0; ot < 4; ++ot) {
        // wz as A-operand: A[o=ot*16+ln][c=h2*32+quad*8+j]
        s8v w0 = *(const s8v*)(wzb + (ot * 16 + ln) * 64 + quad * 8);
        s8v w1 = *(const s8v*)(wzb + (ot * 16 + ln) * 64 + 32 + quad * 8);
        f4 oa = __builtin_amdgcn_mfma_f32_16x16x32_bf16(w0, zf0, zf4, 0, 0, 0);
        oa     = __builtin_amdgcn_mfma_f32_16x16x32_bf16(w1, zf1, oa, 0, 0, 0);
        #pragma unroll
        for (int r = 0; r < 4; ++r) {
            int o = ot * 16 + quad * 4 + r;
            size_t idx = (size_t)(b * CIN + o) * NTOK + n0 + ln;
            out[idx] = oa[r] + bz[o] + h[idx];
        }
    }
}

extern "C" void kernel_launch(void* const* d_in, const int* in_sizes, int n_in,
                              void* d_out, int out_size, void* d_ws, size_t ws_size,
                              hipStream_t stream) {
    (void)in_sizes; (void)n_in; (void)out_size; (void)ws_size;
    const float* h  = (const float*)d_in[0];
    const float* wq = (const float*)d_in[1];
    const float* bq = (const float*)d_in[2];
    const float* wk = (const float*)d_in[3];
    const float* bk = (const float*)d_in[4];
    const float* wv = (const float*)d_in[5];
    const float* bv = (const float*)d_in[6];
    const float* wz = (const float*)d_in[7];
    const float* bz = (const float*)d_in[8];
    float* out = (float*)d_out;

    // workspace layout (shorts): qbf 1M | kbf 1M | vp 2M | wzb 4096  (~8.4 MB)
    short* qbf = (short*)d_ws;
    short* kbf = qbf + (size_t)BATCH * NTOK * DH;
    short* vpw = kbf + (size_t)BATCH * NTOK * DH;
    short* wzb = vpw + (size_t)BATCH * NTOK * CIN;

    proj_kernel<<<dim3(128), dim3(256), 0, stream>>>(
        h, wq, bq, wk, bk, wv, bv, wz, qbf, kbf, vpw, wzb);
    attn_kernel<<<dim3(8, 64), dim3(256), 0, stream>>>(
        h, bz, qbf, kbf, vpw, wzb, out);
}

// Round 2
// 117.329 us; speedup vs baseline: 1.7506x; 1.7506x over previous
//
#include <hip/hip_runtime.h>
#include <stdint.h>

#define BATCH 8
#define CIN   64
#define DH    32
#define NTOK  4096
#define LOG2E 1.4426950408889634f

typedef float    f4   __attribute__((ext_vector_type(4)));
typedef short    s8v  __attribute__((ext_vector_type(8)));
typedef uint32_t u32;
typedef uint32_t u32x2 __attribute__((ext_vector_type(2)));
typedef uint32_t u32x4 __attribute__((ext_vector_type(4)));

static __device__ __forceinline__ short f2bf(float f) {       // RNE
    union { float f; u32 u; } c; c.f = f;
    u32 u = c.u;
    u32 r = (u + 0x7fffu + ((u >> 16) & 1u)) >> 16;
    return (short)(r & 0xffffu);
}
static __device__ __forceinline__ u32 pk2(float a, float b) { // RNE pack
    return (u32)(uint16_t)f2bf(a) | ((u32)(uint16_t)f2bf(b) << 16);
}
static __device__ __forceinline__ u32 pktr(float a, float b) { // truncate pack (fast)
    union { float f; u32 u; } ca, cb; ca.f = a; cb.f = b;
#if __has_builtin(__builtin_amdgcn_perm)
    return __builtin_amdgcn_perm(cb.u, ca.u, 0x07060302u);
#else
    return (cb.u & 0xffff0000u) | (ca.u >> 16);
#endif
}
static __device__ __forceinline__ float bfhi(u32 u) {  // high16 -> f32
    union { u32 u; float f; } c; c.u = u & 0xffff0000u; return c.f;
}
static __device__ __forceinline__ float bflo(u32 u) {  // low16 -> f32
    union { u32 u; float f; } c; c.u = u << 16; return c.f;
}

// ---------------------------------------------------------------------------
// Kernel 1: MFMA-based QKV projection.
//   qbf[b][n][32] = bf16((Wq x + bq) * log2e)   (n-major, d contiguous)
//   kbf[b][n][32] = bf16( Wk x + bk )
//   vp  permuted: key n -> cidx=n>>5, p=n&31, t=p>>4, qq=(p>>2)&3, r=p&3,
//                 j=t*4+r; vp[(((b*128+cidx)*4+qq)*64 + ch)*8 + j]
// Block: one batch x 64-token tile. grid (8, 64), 256 threads.
// ---------------------------------------------------------------------------
__global__ __launch_bounds__(256) void proj_kernel(
    const float* __restrict__ h,
    const float* __restrict__ wq, const float* __restrict__ bq,
    const float* __restrict__ wk, const float* __restrict__ bk,
    const float* __restrict__ wv, const float* __restrict__ bv,
    short* __restrict__ qbf, short* __restrict__ kbf, short* __restrict__ vp)
{
    __shared__ short xT [64 * 72];   // [n_local][c] bf16, stride 72
    __shared__ short wqs[32 * 72];   // [o][c] bf16 (pre-scaled by log2e)
    __shared__ short wks[32 * 72];
    __shared__ short wvs[64 * 72];
    __shared__ float bqs[32], bks[32], bvs[64];

    const int t   = threadIdx.x;
    const int b   = blockIdx.x;
    const int nt0 = blockIdx.y * 64;

    { // stage x tile: coalesced global reads, bf16 transpose into LDS
        const int c  = t >> 2;
        const int ng = (t & 3) * 16;
        const float* src = h + ((size_t)(b * CIN + c)) * NTOK + nt0 + ng;
        f4 x0 = *(const f4*)(src + 0);
        f4 x1 = *(const f4*)(src + 4);
        f4 x2 = *(const f4*)(src + 8);
        f4 x3 = *(const f4*)(src + 12);
        #pragma unroll
        for (int i = 0; i < 4; ++i) {
            xT[(ng + 0  + i) * 72 + c] = f2bf(x0[i]);
            xT[(ng + 4  + i) * 72 + c] = f2bf(x1[i]);
            xT[(ng + 8  + i) * 72 + c] = f2bf(x2[i]);
            xT[(ng + 12 + i) * 72 + c] = f2bf(x3[i]);
        }
    }
    for (int idx = t; idx < 2048; idx += 256) {
        int o = idx >> 6, c = idx & 63;
        wqs[o * 72 + c] = f2bf(wq[idx] * LOG2E);
        wks[o * 72 + c] = f2bf(wk[idx]);
    }
    for (int idx = t; idx < 4096; idx += 256)
        wvs[(idx >> 6) * 72 + (idx & 63)] = f2bf(wv[idx]);
    if (t < 32) { bqs[t] = bq[t] * LOG2E; bks[t] = bk[t]; }
    if (t < 64) bvs[t] = bv[t];
    __syncthreads();

    const int w    = t >> 6;
    const int ln   = t & 15;
    const int quad = (t >> 4) & 3;
    const int n    = nt0 + w * 16 + ln;    // this lane's token (MFMA column)
    const f4 zf4 = {0.f, 0.f, 0.f, 0.f};

    const s8v xb0 = *(const s8v*)&xT[(w * 16 + ln) * 72 + quad * 8];
    const s8v xb1 = *(const s8v*)&xT[(w * 16 + ln) * 72 + 32 + quad * 8];

    // ---- q, k (2 o-tiles each) ----
    #pragma unroll
    for (int ot = 0; ot < 2; ++ot) {
        s8v a0 = *(const s8v*)&wqs[(ot * 16 + ln) * 72 + quad * 8];
        s8v a1 = *(const s8v*)&wqs[(ot * 16 + ln) * 72 + 32 + quad * 8];
        f4 d = __builtin_amdgcn_mfma_f32_16x16x32_bf16(a0, xb0, zf4, 0, 0, 0);
        d     = __builtin_amdgcn_mfma_f32_16x16x32_bf16(a1, xb1, d,  0, 0, 0);
        f4 bb = *(const f4*)&bqs[ot * 16 + quad * 4];
        u32x2 pw; pw[0] = pk2(d[0] + bb[0], d[1] + bb[1]);
                  pw[1] = pk2(d[2] + bb[2], d[3] + bb[3]);
        *(u32x2*)(qbf + ((size_t)(b * NTOK + n)) * DH + ot * 16 + quad * 4) = pw;

        s8v c0 = *(const s8v*)&wks[(ot * 16 + ln) * 72 + quad * 8];
        s8v c1 = *(const s8v*)&wks[(ot * 16 + ln) * 72 + 32 + quad * 8];
        f4 e = __builtin_amdgcn_mfma_f32_16x16x32_bf16(c0, xb0, zf4, 0, 0, 0);
        e     = __builtin_amdgcn_mfma_f32_16x16x32_bf16(c1, xb1, e,  0, 0, 0);
        f4 kb = *(const f4*)&bks[ot * 16 + quad * 4];
        u32x2 kw; kw[0] = pk2(e[0] + kb[0], e[1] + kb[1]);
                  kw[1] = pk2(e[2] + kb[2], e[3] + kb[3]);
        *(u32x2*)(kbf + ((size_t)(b * NTOK + n)) * DH + ot * 16 + quad * 4) = kw;
    }

    // ---- v (4 o-tiles), scattered permuted store ----
    {
        const int cidx = n >> 5, p = n & 31;
        const int tt = p >> 4, qq = (p >> 2) & 3, r0 = p & 3;
        const int j = tt * 4 + r0;
        short* vdst = vp + ((size_t)((b * 128 + cidx) * 4 + qq) * 64) * 8 + j;
        #pragma unroll
        for (int ot = 0; ot < 4; ++ot) {
            s8v a0 = *(const s8v*)&wvs[(ot * 16 + ln) * 72 + quad * 8];
            s8v a1 = *(const s8v*)&wvs[(ot * 16 + ln) * 72 + 32 + quad * 8];
            f4 d = __builtin_amdgcn_mfma_f32_16x16x32_bf16(a0, xb0, zf4, 0, 0, 0);
            d     = __builtin_amdgcn_mfma_f32_16x16x32_bf16(a1, xb1, d,  0, 0, 0);
            #pragma unroll
            for (int r = 0; r < 4; ++r) {
                int ch = ot * 16 + quad * 4 + r;
                vdst[ch * 8] = f2bf(d[r] + bvs[ch]);
            }
        }
    }
}

// ---------------------------------------------------------------------------
// Kernel 2: max-free flash attention + Wz projection + residual.
// Block: 512 threads = 8 waves = 2 query-halves x 4 key-sections.
// Each wave: 64 queries (4 frags) x 1024 keys. Block: 128 queries, full K.
// grid (8, 32): batch pinned to XCD, 1 block/CU.
// ---------------------------------------------------------------------------
__global__ __launch_bounds__(512, 2) void attn_kernel(
    const float* __restrict__ h,  const float* __restrict__ wz,
    const float* __restrict__ bz,
    const short* __restrict__ qbf, const short* __restrict__ kbf,
    const short* __restrict__ vp,  float* __restrict__ out)
{
    __shared__ short accb[4][64][72];   // bf16 partial acc slots, 36.9 KB
    __shared__ short zbuf[128][72];     // normalized z [query][ch], 18.4 KB
    __shared__ float lbuf[8][64];       // per-wave partial l, 2 KB

    const int b    = blockIdx.x;
    const int qb0  = blockIdx.y * 128;
    const int tid  = threadIdx.x;
    const int w    = tid >> 6;
    const int lane = tid & 63;
    const int ln   = lane & 15;
    const int quad = lane >> 4;
    const int qh   = w >> 2;            // query half
    const int ksec = w & 3;             // key quarter
    const int nbase = qb0 + qh * 64;
    const f4 zf4 = {0.f, 0.f, 0.f, 0.f};

    // Q fragments (B-operand): B[d=quad*8+j][n=ln]
    s8v qf[4];
    #pragma unroll
    for (int f = 0; f < 4; ++f)
        qf[f] = *(const s8v*)(qbf + ((size_t)(b * NTOK + nbase + f * 16 + ln)) * DH + quad * 8);

    f4 acc[4][4];
    f4 accl[4];
    #pragma unroll
    for (int f = 0; f < 4; ++f) {
        accl[f] = zf4;
        #pragma unroll
        for (int ct = 0; ct < 4; ++ct) acc[f][ct] = zf4;
    }
    s8v ones;
    #pragma unroll
    for (int j = 0; j < 8; ++j) ones[j] = (short)0x3F80;   // bf16 1.0

    const short* kb = kbf + (size_t)b * NTOK * DH;
    const s8v*   vb = (const s8v*)(vp + (size_t)b * NTOK * CIN);

    const int kend = ksec * 1024 + 1024;
    for (int kt = ksec * 1024; kt < kend; kt += 32) {
        s8v kk0 = *(const s8v*)(kb + (kt + ln) * DH + quad * 8);
        s8v kk1 = *(const s8v*)(kb + (kt + 16 + ln) * DH + quad * 8);
        const s8v* vg = vb + (size_t)((kt >> 5) * 4 + quad) * 64 + ln;
        s8v v0 = vg[0], v1 = vg[16], v2 = vg[32], v3 = vg[48];

        #pragma unroll
        for (int f = 0; f < 4; ++f) {
            f4 sa = __builtin_amdgcn_mfma_f32_16x16x32_bf16(kk0, qf[f], zf4, 0, 0, 0);
            f4 sb = __builtin_amdgcn_mfma_f32_16x16x32_bf16(kk1, qf[f], zf4, 0, 0, 0);
            f4 ea, eb;
            #pragma unroll
            for (int r = 0; r < 4; ++r) {
                ea[r] = __builtin_amdgcn_exp2f(sa[r]);   // scores pre-scaled by log2e
                eb[r] = __builtin_amdgcn_exp2f(sb[r]);
            }
            u32x4 pd;
            pd[0] = pktr(ea[0], ea[1]); pd[1] = pktr(ea[2], ea[3]);
            pd[2] = pktr(eb[0], eb[1]); pd[3] = pktr(eb[2], eb[3]);
            s8v pf = __builtin_bit_cast(s8v, pd);

            accl[f]   = __builtin_amdgcn_mfma_f32_16x16x32_bf16(ones, pf, accl[f],   0, 0, 0);
            acc[f][0] = __builtin_amdgcn_mfma_f32_16x16x32_bf16(v0,   pf, acc[f][0], 0, 0, 0);
            acc[f][1] = __builtin_amdgcn_mfma_f32_16x16x32_bf16(v1,   pf, acc[f][1], 0, 0, 0);
            acc[f][2] = __builtin_amdgcn_mfma_f32_16x16x32_bf16(v2,   pf, acc[f][2], 0, 0, 0);
            acc[f][3] = __builtin_amdgcn_mfma_f32_16x16x32_bf16(v3,   pf, acc[f][3], 0, 0, 0);
        }
    }

    // ---- combine the 2x4 partials through LDS ----
    if (quad == 0) {
        #pragma unroll
        for (int f = 0; f < 4; ++f) lbuf[w][f * 16 + ln] = accl[f][0];
    }
    #define WRITE_SLOT(slot)                                                        \
        {                                                                           \
            _Pragma("unroll")                                                       \
            for (int f = 0; f < 4; ++f) {                                           \
                _Pragma("unroll")                                                   \
                for (int ct = 0; ct < 4; ++ct) {                                    \
                    u32x2 pw;                                                       \
                    pw[0] = pk2(acc[f][ct][0], acc[f][ct][1]);                      \
                    pw[1] = pk2(acc[f][ct][2], acc[f][ct][3]);                      \
                    *(u32x2*)&accb[slot][f * 16 + ln][ct * 16 + quad * 4] = pw;     \
                }                                                                   \
            }                                                                       \
        }
    if (w < 4) WRITE_SLOT(w);
    __syncthreads();

    #define COMBINE(half)                                                           \
        if (tid < 256) {                                                            \
            const int q   = tid >> 2;                                               \
            const int chg = (tid & 3) * 16;                                         \
            float ls = lbuf[(half) * 4 + 0][q] + lbuf[(half) * 4 + 1][q] +          \
                       lbuf[(half) * 4 + 2][q] + lbuf[(half) * 4 + 3][q];           \
            float rl = __builtin_amdgcn_rcpf(ls);                                   \
            float zv[16];                                                           \
            _Pragma("unroll")                                                       \
            for (int i = 0; i < 16; ++i) zv[i] = 0.f;                               \
            _Pragma("unroll")                                                       \
            for (int w2 = 0; w2 < 4; ++w2) {                                        \
                u32x4 ua = *(u32x4*)&accb[w2][q][chg];                              \
                u32x4 ub = *(u32x4*)&accb[w2][q][chg + 8];                          \
                _Pragma("unroll")                                                   \
                for (int d = 0; d < 4; ++d) {                                       \
                    zv[d * 2]     += bflo(ua[d]); zv[d * 2 + 1]     += bfhi(ua[d]); \
                    zv[8 + d * 2] += bflo(ub[d]); zv[8 + d * 2 + 1] += bfhi(ub[d]); \
                }                                                                   \
            }                                                                       \
            u32x4 za, zb2;                                                          \
            _Pragma("unroll")                                                       \
            for (int d = 0; d < 4; ++d) {                                           \
                za[d]  = pk2(zv[d * 2] * rl,     zv[d * 2 + 1] * rl);               \
                zb2[d] = pk2(zv[8 + d * 2] * rl, zv[8 + d * 2 + 1] * rl);           \
            }                                                                       \
            *(u32x4*)&zbuf[(half) * 64 + q][chg]     = za;                          \
            *(u32x4*)&zbuf[(half) * 64 + q][chg + 8] = zb2;                         \
        }
    COMBINE(0);
    __syncthreads();
    if (w >= 4) WRITE_SLOT(w - 4);
    __syncthreads();
    COMBINE(1);
    __syncthreads();

    // ---- out-projection: wave w handles o-tile (w&3) for query group (w>>2) ----
    {
        const int ot = w & 3, g = w >> 2;
        s8v wzf[2];
        #pragma unroll
        for (int half = 0; half < 2; ++half) {
            const float* wp = wz + (ot * 16 + ln) * 64 + half * 32 + quad * 8;
            f4 wa = *(const f4*)wp;
            f4 wb = *(const f4*)(wp + 4);
            u32x4 tt;
            tt[0] = pk2(wa[0], wa[1]); tt[1] = pk2(wa[2], wa[3]);
            tt[2] = pk2(wb[0], wb[1]); tt[3] = pk2(wb[2], wb[3]);
            wzf[half] = __builtin_bit_cast(s8v, tt);
        }
        f4 bzv = *(const f4*)(bz + ot * 16 + quad * 4);
        #pragma unroll
        for (int fi = 0; fi < 4; ++fi) {
            const int row = g * 64 + fi * 16 + ln;
            s8v z0 = *(const s8v*)&zbuf[row][quad * 8];
            s8v z1 = *(const s8v*)&zbuf[row][32 + quad * 8];
            f4 oa = __builtin_amdgcn_mfma_f32_16x16x32_bf16(wzf[0], z0, zf4, 0, 0, 0);
            oa     = __builtin_amdgcn_mfma_f32_16x16x32_bf16(wzf[1], z1, oa,  0, 0, 0);
            #pragma unroll
            for (int r = 0; r < 4; ++r) {
                size_t idx = ((size_t)(b * CIN + ot * 16 + quad * 4 + r)) * NTOK
                           + qb0 + row;
                out[idx] = oa[r] + bzv[r] + h[idx];
            }
        }
    }
}

extern "C" void kernel_launch(void* const* d_in, const int* in_sizes, int n_in,
                              void* d_out, int out_size, void* d_ws, size_t ws_size,
                              hipStream_t stream) {
    (void)in_sizes; (void)n_in; (void)out_size; (void)ws_size;
    const float* h  = (const float*)d_in[0];
    const float* wq = (const float*)d_in[1];
    const float* bq = (const float*)d_in[2];
    const float* wk = (const float*)d_in[3];
    const float* bk = (const float*)d_in[4];
    const float* wv = (const float*)d_in[5];
    const float* bv = (const float*)d_in[6];
    const float* wz = (const float*)d_in[7];
    const float* bz = (const float*)d_in[8];
    float* out = (float*)d_out;

    short* qbf = (short*)d_ws;                                // 8*4096*32
    short* kbf = qbf + (size_t)BATCH * NTOK * DH;             // 8*4096*32
    short* vpw = kbf + (size_t)BATCH * NTOK * DH;             // 8*4096*64

    proj_kernel<<<dim3(8, 64), dim3(256), 0, stream>>>(
        h, wq, bq, wk, bk, wv, bv, qbf, kbf, vpw);
    attn_kernel<<<dim3(8, 32), dim3(512), 0, stream>>>(
        h, wz, bz, qbf, kbf, vpw, out);
}

// Round 4
// 115.694 us; speedup vs baseline: 1.7754x; 1.0141x over previous
//
#include <hip/hip_runtime.h>
#include <stdint.h>

#define BATCH 8
#define CIN   64
#define DH    32
#define NTOK  4096
#define LOG2E 1.4426950408889634f

typedef float    f4   __attribute__((ext_vector_type(4)));
typedef short    s8v  __attribute__((ext_vector_type(8)));
typedef uint32_t u32;
typedef uint32_t u32x2 __attribute__((ext_vector_type(2)));
typedef uint32_t u32x4 __attribute__((ext_vector_type(4)));

static __device__ __forceinline__ short f2bf(float f) {       // RNE
    union { float f; u32 u; } c; c.f = f;
    u32 u = c.u;
    u32 r = (u + 0x7fffu + ((u >> 16) & 1u)) >> 16;
    return (short)(r & 0xffffu);
}
static __device__ __forceinline__ u32 pk2(float a, float b) { // RNE pack
    return (u32)(uint16_t)f2bf(a) | ((u32)(uint16_t)f2bf(b) << 16);
}
static __device__ __forceinline__ u32 pktr(float a, float b) { // truncate pack (fast)
    union { float f; u32 u; } ca, cb; ca.f = a; cb.f = b;
#if __has_builtin(__builtin_amdgcn_perm)
    return __builtin_amdgcn_perm(cb.u, ca.u, 0x07060302u);
#else
    return (cb.u & 0xffff0000u) | (ca.u >> 16);
#endif
}
static __device__ __forceinline__ float bfhi(u32 u) {
    union { u32 u; float f; } c; c.u = u & 0xffff0000u; return c.f;
}
static __device__ __forceinline__ float bflo(u32 u) {
    union { u32 u; float f; } c; c.u = u << 16; return c.f;
}

// ---------------------------------------------------------------------------
// Kernel 1: MFMA QKV projection.
//   qbf[b][n][32] = bf16((Wq x + bq) * log2e)   (n-major, d contiguous)
//   kbf[b][n][32] = bf16( Wk x + bk )
//   vp  permuted: key n -> cidx=n>>5, p=n&31, qq=(p>>2)&3, j=(p>>4)*4+(p&3);
//                 vp[(((b*128+cidx)*4+qq)*64 + ch)*8 + j]
// V goes through an LDS transpose (vls2) so the global store is coalesced
// dwordx4. Block region = 64 tok x 64 ch = 4096 shorts = 512 u32x4 slots;
// copy-out: 256 threads x 2 slots (round-3 bug was 4 slots -> 8KB overrun).
// Block: one batch x 64-token tile. grid (8, 64), 256 threads.
// ---------------------------------------------------------------------------
__global__ __launch_bounds__(256) void proj_kernel(
    const float* __restrict__ h,
    const float* __restrict__ wq, const float* __restrict__ bq,
    const float* __restrict__ wk, const float* __restrict__ bk,
    const float* __restrict__ wv, const float* __restrict__ bv,
    short* __restrict__ qbf, short* __restrict__ kbf, short* __restrict__ vp)
{
    __shared__ short xT [64 * 72];   // [n_local][c] bf16
    __shared__ short wqs[32 * 72];   // [o][c] bf16 (pre-scaled by log2e)
    __shared__ short wks[32 * 72];
    __shared__ short wvs[64 * 72];
    __shared__ short vls2[64 * 68];  // [row=cid2*32+qq*8+j][ch], pad 68
    __shared__ float bqs[32], bks[32], bvs[64];

    const int t   = threadIdx.x;
    const int b   = blockIdx.x;
    const int nt0 = blockIdx.y * 64;

    { // stage x tile: coalesced global reads, bf16 transpose into LDS
        const int c  = t >> 2;
        const int ng = (t & 3) * 16;
        const float* src = h + ((size_t)(b * CIN + c)) * NTOK + nt0 + ng;
        f4 x0 = *(const f4*)(src + 0);
        f4 x1 = *(const f4*)(src + 4);
        f4 x2 = *(const f4*)(src + 8);
        f4 x3 = *(const f4*)(src + 12);
        #pragma unroll
        for (int i = 0; i < 4; ++i) {
            xT[(ng + 0  + i) * 72 + c] = f2bf(x0[i]);
            xT[(ng + 4  + i) * 72 + c] = f2bf(x1[i]);
            xT[(ng + 8  + i) * 72 + c] = f2bf(x2[i]);
            xT[(ng + 12 + i) * 72 + c] = f2bf(x3[i]);
        }
    }
    for (int idx = t; idx < 2048; idx += 256) {
        int o = idx >> 6, c = idx & 63;
        wqs[o * 72 + c] = f2bf(wq[idx] * LOG2E);
        wks[o * 72 + c] = f2bf(wk[idx]);
    }
    for (int idx = t; idx < 4096; idx += 256)
        wvs[(idx >> 6) * 72 + (idx & 63)] = f2bf(wv[idx]);
    if (t < 32) { bqs[t] = bq[t] * LOG2E; bks[t] = bk[t]; }
    if (t < 64) bvs[t] = bv[t];
    __syncthreads();

    const int w    = t >> 6;
    const int ln   = t & 15;
    const int quad = (t >> 4) & 3;
    const int nl   = w * 16 + ln;          // local token (MFMA column)
    const int n    = nt0 + nl;
    const f4 zf4 = {0.f, 0.f, 0.f, 0.f};

    const s8v xb0 = *(const s8v*)&xT[nl * 72 + quad * 8];
    const s8v xb1 = *(const s8v*)&xT[nl * 72 + 32 + quad * 8];

    // ---- q, k (2 o-tiles each) ----
    #pragma unroll
    for (int ot = 0; ot < 2; ++ot) {
        s8v a0 = *(const s8v*)&wqs[(ot * 16 + ln) * 72 + quad * 8];
        s8v a1 = *(const s8v*)&wqs[(ot * 16 + ln) * 72 + 32 + quad * 8];
        f4 d = __builtin_amdgcn_mfma_f32_16x16x32_bf16(a0, xb0, zf4, 0, 0, 0);
        d     = __builtin_amdgcn_mfma_f32_16x16x32_bf16(a1, xb1, d,  0, 0, 0);
        f4 bb = *(const f4*)&bqs[ot * 16 + quad * 4];
        u32x2 pw; pw[0] = pk2(d[0] + bb[0], d[1] + bb[1]);
                  pw[1] = pk2(d[2] + bb[2], d[3] + bb[3]);
        *(u32x2*)(qbf + ((size_t)(b * NTOK + n)) * DH + ot * 16 + quad * 4) = pw;

        s8v c0 = *(const s8v*)&wks[(ot * 16 + ln) * 72 + quad * 8];
        s8v c1 = *(const s8v*)&wks[(ot * 16 + ln) * 72 + 32 + quad * 8];
        f4 e = __builtin_amdgcn_mfma_f32_16x16x32_bf16(c0, xb0, zf4, 0, 0, 0);
        e     = __builtin_amdgcn_mfma_f32_16x16x32_bf16(c1, xb1, e,  0, 0, 0);
        f4 kb = *(const f4*)&bks[ot * 16 + quad * 4];
        u32x2 kw; kw[0] = pk2(e[0] + kb[0], e[1] + kb[1]);
                  kw[1] = pk2(e[2] + kb[2], e[3] + kb[3]);
        *(u32x2*)(kbf + ((size_t)(b * NTOK + n)) * DH + ot * 16 + quad * 4) = kw;
    }

    // ---- v (4 o-tiles) -> packed LDS writes at permuted rows ----
    {
        const int p    = nl & 31;
        const int row  = (nl >> 5) * 32 + ((p >> 2) & 3) * 8   // cid2*32 + qq*8
                       + (p >> 4) * 4 + (p & 3);               // + j
        short* vrow = &vls2[row * 68];
        #pragma unroll
        for (int ot = 0; ot < 4; ++ot) {
            s8v a0 = *(const s8v*)&wvs[(ot * 16 + ln) * 72 + quad * 8];
            s8v a1 = *(const s8v*)&wvs[(ot * 16 + ln) * 72 + 32 + quad * 8];
            f4 d = __builtin_amdgcn_mfma_f32_16x16x32_bf16(a0, xb0, zf4, 0, 0, 0);
            d     = __builtin_amdgcn_mfma_f32_16x16x32_bf16(a1, xb1, d,  0, 0, 0);
            const int ch = ot * 16 + quad * 4;
            u32x2 pw;
            pw[0] = pk2(d[0] + bvs[ch],     d[1] + bvs[ch + 1]);
            pw[1] = pk2(d[2] + bvs[ch + 2], d[3] + bvs[ch + 3]);
            *(u32x2*)&vrow[ch] = pw;
        }
    }
    __syncthreads();

    // ---- coalesced copy-out of the block's contiguous 8 KB vp region ----
    {
        const int g = t >> 5;            // cid2*4 + qq, 0..7
        const int r = t & 31;            // ch pair index
        short tmp[16];
        #pragma unroll
        for (int j = 0; j < 8; ++j)
            #pragma unroll
            for (int cc = 0; cc < 2; ++cc)
                tmp[cc * 8 + j] = vls2[(g * 8 + j) * 68 + r * 2 + cc];
        u32x4* dst = (u32x4*)(vp + ((size_t)(b * 128 + blockIdx.y * 2) * 4) * 64 * 8);
        #pragma unroll
        for (int i = 0; i < 2; ++i)
            dst[t * 2 + i] = ((const u32x4*)tmp)[i];
    }
}

// ---------------------------------------------------------------------------
// Kernel 2: max-free flash attention + Wz projection + residual.
// Block: 256 threads = 4 waves = 4 key-sections, 64 queries.
// grid (8, 64): batch pinned to XCD, 2 blocks/CU (barriers overlap).
// ---------------------------------------------------------------------------
__global__ __launch_bounds__(256, 2) void attn_kernel(
    const float* __restrict__ h,  const float* __restrict__ wz,
    const float* __restrict__ bz,
    const short* __restrict__ qbf, const short* __restrict__ kbf,
    const short* __restrict__ vp,  float* __restrict__ out)
{
    __shared__ short accb[4][64][72];   // bf16 partial acc slots, 36.9 KB
    __shared__ short zbuf[64][72];      // normalized z [query][ch], 9.2 KB
    __shared__ float lbuf[4][64];       // per-wave partial l, 1 KB

    const int b    = blockIdx.x;
    const int qb0  = blockIdx.y * 64;
    const int tid  = threadIdx.x;
    const int w    = tid >> 6;          // wave = key quarter
    const int lane = tid & 63;
    const int ln   = lane & 15;
    const int quad = lane >> 4;
    const f4 zf4 = {0.f, 0.f, 0.f, 0.f};

    // Q fragments (B-operand): B[d=quad*8+j][n=ln]
    s8v qf[4];
    #pragma unroll
    for (int f = 0; f < 4; ++f)
        qf[f] = *(const s8v*)(qbf + ((size_t)(b * NTOK + qb0 + f * 16 + ln)) * DH + quad * 8);

    f4 acc[4][4];
    f4 accl[4];
    #pragma unroll
    for (int f = 0; f < 4; ++f) {
        accl[f] = zf4;
        #pragma unroll
        for (int ct = 0; ct < 4; ++ct) acc[f][ct] = zf4;
    }
    s8v ones;
    #pragma unroll
    for (int j = 0; j < 8; ++j) ones[j] = (short)0x3F80;   // bf16 1.0

    const short* kb2 = kbf + ((size_t)b * NTOK + w * 1024) * DH;
    const s8v*   vb2 = (const s8v*)(vp + (size_t)b * NTOK * CIN)
                     + (size_t)(w * 32) * 4 * 64;

    for (int kt = 0; kt < 1024; kt += 32) {
        const short* kp = kb2 + kt * DH;
        s8v kk0 = *(const s8v*)(kp + ln * DH + quad * 8);
        s8v kk1 = *(const s8v*)(kp + (16 + ln) * DH + quad * 8);
        const s8v* vg = vb2 + (size_t)((kt >> 5) * 4 + quad) * 64 + ln;
        s8v v0 = vg[0], v1 = vg[16], v2 = vg[32], v3 = vg[48];

        #pragma unroll
        for (int f = 0; f < 4; ++f) {
            f4 sa = __builtin_amdgcn_mfma_f32_16x16x32_bf16(kk0, qf[f], zf4, 0, 0, 0);
            f4 sb = __builtin_amdgcn_mfma_f32_16x16x32_bf16(kk1, qf[f], zf4, 0, 0, 0);
            f4 ea, eb;
            #pragma unroll
            for (int r = 0; r < 4; ++r) {
                ea[r] = __builtin_amdgcn_exp2f(sa[r]);   // scores pre-scaled by log2e
                eb[r] = __builtin_amdgcn_exp2f(sb[r]);
            }
            u32x4 pd;
            pd[0] = pktr(ea[0], ea[1]); pd[1] = pktr(ea[2], ea[3]);
            pd[2] = pktr(eb[0], eb[1]); pd[3] = pktr(eb[2], eb[3]);
            s8v pf = __builtin_bit_cast(s8v, pd);

            accl[f]   = __builtin_amdgcn_mfma_f32_16x16x32_bf16(ones, pf, accl[f],   0, 0, 0);
            acc[f][0] = __builtin_amdgcn_mfma_f32_16x16x32_bf16(v0,   pf, acc[f][0], 0, 0, 0);
            acc[f][1] = __builtin_amdgcn_mfma_f32_16x16x32_bf16(v1,   pf, acc[f][1], 0, 0, 0);
            acc[f][2] = __builtin_amdgcn_mfma_f32_16x16x32_bf16(v2,   pf, acc[f][2], 0, 0, 0);
            acc[f][3] = __builtin_amdgcn_mfma_f32_16x16x32_bf16(v3,   pf, acc[f][3], 0, 0, 0);
        }
    }

    // ---- write partials (one slot per wave), single combine phase ----
    if (quad == 0) {
        #pragma unroll
        for (int f = 0; f < 4; ++f) lbuf[w][f * 16 + ln] = accl[f][0];
    }
    #pragma unroll
    for (int f = 0; f < 4; ++f) {
        #pragma unroll
        for (int ct = 0; ct < 4; ++ct) {
            u32x2 pw;
            pw[0] = pk2(acc[f][ct][0], acc[f][ct][1]);
            pw[1] = pk2(acc[f][ct][2], acc[f][ct][3]);
            *(u32x2*)&accb[w][f * 16 + ln][ct * 16 + quad * 4] = pw;
        }
    }
    __syncthreads();

    {
        const int q   = tid >> 2;
        const int chg = (tid & 3) * 16;
        float ls = lbuf[0][q] + lbuf[1][q] + lbuf[2][q] + lbuf[3][q];
        float rl = __builtin_amdgcn_rcpf(ls);
        float zv[16];
        #pragma unroll
        for (int i = 0; i < 16; ++i) zv[i] = 0.f;
        #pragma unroll
        for (int w2 = 0; w2 < 4; ++w2) {
            u32x4 ua = *(u32x4*)&accb[w2][q][chg];
            u32x4 ub = *(u32x4*)&accb[w2][q][chg + 8];
            #pragma unroll
            for (int d = 0; d < 4; ++d) {
                zv[d * 2]     += bflo(ua[d]); zv[d * 2 + 1]     += bfhi(ua[d]);
                zv[8 + d * 2] += bflo(ub[d]); zv[8 + d * 2 + 1] += bfhi(ub[d]);
            }
        }
        u32x4 za, zb2;
        #pragma unroll
        for (int d = 0; d < 4; ++d) {
            za[d]  = pk2(zv[d * 2] * rl,     zv[d * 2 + 1] * rl);
            zb2[d] = pk2(zv[8 + d * 2] * rl, zv[8 + d * 2 + 1] * rl);
        }
        *(u32x4*)&zbuf[q][chg]     = za;
        *(u32x4*)&zbuf[q][chg + 8] = zb2;
    }
    __syncthreads();

    // ---- out-projection: wave w handles o-tile w for all 64 queries ----
    {
        const int ot = w;
        s8v wzf[2];
        #pragma unroll
        for (int half = 0; half < 2; ++half) {
            const float* wp = wz + (ot * 16 + ln) * 64 + half * 32 + quad * 8;
            f4 wa = *(const f4*)wp;
            f4 wb = *(const f4*)(wp + 4);
            u32x4 tt;
            tt[0] = pk2(wa[0], wa[1]); tt[1] = pk2(wa[2], wa[3]);
            tt[2] = pk2(wb[0], wb[1]); tt[3] = pk2(wb[2], wb[3]);
            wzf[half] = __builtin_bit_cast(s8v, tt);
        }
        f4 bzv = *(const f4*)(bz + ot * 16 + quad * 4);
        #pragma unroll
        for (int fi = 0; fi < 4; ++fi) {
            const int row = fi * 16 + ln;
            s8v z0 = *(const s8v*)&zbuf[row][quad * 8];
            s8v z1 = *(const s8v*)&zbuf[row][32 + quad * 8];
            f4 oa = __builtin_amdgcn_mfma_f32_16x16x32_bf16(wzf[0], z0, zf4, 0, 0, 0);
            oa     = __builtin_amdgcn_mfma_f32_16x16x32_bf16(wzf[1], z1, oa,  0, 0, 0);
            #pragma unroll
            for (int r = 0; r < 4; ++r) {
                size_t idx = ((size_t)(b * CIN + ot * 16 + quad * 4 + r)) * NTOK
                           + qb0 + row;
                out[idx] = oa[r] + bzv[r] + h[idx];
            }
        }
    }
}

extern "C" void kernel_launch(void* const* d_in, const int* in_sizes, int n_in,
                              void* d_out, int out_size, void* d_ws, size_t ws_size,
                              hipStream_t stream) {
    (void)in_sizes; (void)n_in; (void)out_size; (void)ws_size;
    const float* h  = (const float*)d_in[0];
    const float* wq = (const float*)d_in[1];
    const float* bq = (const float*)d_in[2];
    const float* wk = (const float*)d_in[3];
    const float* bk = (const float*)d_in[4];
    const float* wv = (const float*)d_in[5];
    const float* bv = (const float*)d_in[6];
    const float* wz = (const float*)d_in[7];
    const float* bz = (const float*)d_in[8];
    float* out = (float*)d_out;

    short* qbf = (short*)d_ws;                                // 8*4096*32
    short* kbf = qbf + (size_t)BATCH * NTOK * DH;             // 8*4096*32
    short* vpw = kbf + (size_t)BATCH * NTOK * DH;             // 8*4096*64

    proj_kernel<<<dim3(8, 64), dim3(256), 0, stream>>>(
        h, wq, bq, wk, bk, wv, bv, qbf, kbf, vpw);
    attn_kernel<<<dim3(8, 64), dim3(256), 0, stream>>>(
        h, wz, bz, qbf, kbf, vpw, out);
}